// Round 17
// baseline (85.262 us; speedup 1.0000x reference)
//
#include <hip/hip_runtime.h>
#include <math.h>

#define NPTS 1024
#define HID 64

typedef float v4f __attribute__((ext_vector_type(4)));

// ---------------------------------------------------------------------------
// Kernel A (R13/R14 version): ONE WAVE per row i. 16 distances/lane (exact
// fp32 on the density-count path). Selection of the smallest 32 via per-lane
// bitonic sort(16) + 6-step butterfly keep-min-32 merge (exact multiset).
// Entropies per-lane VALU. Launched TWICE this round (idempotent) to measure
// its standalone duration as the marginal dur_us vs R14's 68.5.
// ---------------------------------------------------------------------------
__global__ __launch_bounds__(64) void k_rows(const float* __restrict__ pts,
                                             float* __restrict__ density,
                                             float* __restrict__ ent,
                                             unsigned int* __restrict__ icnt) {
    const int i    = blockIdx.x;
    const int lane = threadIdx.x;

    const float px = pts[i * 3 + 0];
    const float py = pts[i * 3 + 1];
    const float pz = pts[i * 3 + 2];

    // 16 distances per lane, registers only (static indices).
    float v[16];
    int c0 = 0, c1 = 0, c2 = 0;
    #pragma unroll
    for (int q = 0; q < 16; ++q) {
        const int j = lane + q * 64;              // coalesced across lanes
        // exact rounding, no fma contraction: ((dx*dx + dy*dy) + dz*dz)
        float dx = __fsub_rn(px, pts[j * 3 + 0]);
        float dy = __fsub_rn(py, pts[j * 3 + 1]);
        float dz = __fsub_rn(pz, pts[j * 3 + 2]);
        float d2 = __fadd_rn(__fadd_rn(__fmul_rn(dx, dx), __fmul_rn(dy, dy)),
                             __fmul_rn(dz, dz));
        float d = __fsqrt_rn(d2 > 0.0f ? d2 : 1e-12f);   // _safe_sqrt
        v[q] = d;
        c0 += (d < 0.1f);
        c1 += (d < 0.2f);
        c2 += (d < 0.4f);
    }

    // Pack counts into one ull (21-bit fields), single butterfly reduce.
    unsigned long long packed = (unsigned long long)c0
                              | ((unsigned long long)c1 << 21)
                              | ((unsigned long long)c2 << 42);
    #pragma unroll
    for (int off = 32; off > 0; off >>= 1) packed += __shfl_xor(packed, off);
    // every lane now holds the row totals

    // ---- per-lane bitonic sort of the 16 values (ascending), pure VALU ----
    #pragma unroll
    for (int k = 2; k <= 16; k <<= 1) {
        #pragma unroll
        for (int j = k >> 1; j > 0; j >>= 1) {
            #pragma unroll
            for (int r = 0; r < 16; ++r) {
                const int l = r ^ j;
                if (l > r) {
                    const bool up = ((r & k) == 0);
                    float lo = fminf(v[r], v[l]);
                    float hi = fmaxf(v[r], v[l]);
                    v[r] = up ? lo : hi;
                    v[l] = up ? hi : lo;
                }
            }
        }
    }

    // ---- pad to sorted-32, butterfly keep-min-32 merge across 64 lanes ----
    float s[32];
    #pragma unroll
    for (int r = 0; r < 16; ++r) { s[r] = v[r]; s[16 + r] = 3.0e38f; }

    #pragma unroll
    for (int step = 1; step < 64; step <<= 1) {
        float o[32];
        #pragma unroll
        for (int r = 0; r < 32; ++r) o[r] = __shfl_xor(s[r], step);
        // bitonic halver: lower half of [s, reverse(o)] = smallest 32 (bitonic)
        float m[32];
        #pragma unroll
        for (int r = 0; r < 32; ++r) m[r] = fminf(s[r], o[31 - r]);
        // bitonic clean -> ascending
        #pragma unroll
        for (int j = 16; j > 0; j >>= 1) {
            #pragma unroll
            for (int r = 0; r < 32; ++r) {
                const int l = r ^ j;
                if (l > r) {
                    float lo = fminf(m[r], m[l]);
                    float hi = fmaxf(m[r], m[l]);
                    m[r] = lo;
                    m[l] = hi;
                }
            }
        }
        #pragma unroll
        for (int r = 0; r < 32; ++r) s[r] = m[r];
    }
    // s[0..31]: global sorted 32 smallest (s[0] = self), identical in all lanes

    // ---- entropies over ranks 1..k — pure per-lane VALU, static indices ----
    const int kvv[3] = {5, 10, 25};
    float E[3];
    #pragma unroll
    for (int q = 0; q < 3; ++q) {
        const int k = kvv[q];
        float S = 0.0f;
        #pragma unroll
        for (int r = 1; r <= 25; ++r) if (r <= k) S += s[r];
        float Ee = 0.0f;
        #pragma unroll
        for (int r = 1; r <= 25; ++r) if (r <= k) {
            float p = s[r] / S;
            Ee -= p * logf(p + 1e-10f);
        }
        E[q] = Ee;
    }

    if (lane == 0) {
        ent[i * 3 + 0] = E[0];
        ent[i * 3 + 1] = E[1];
        ent[i * 3 + 2] = E[2];
        const float scl[3] = {0.1f, 0.2f, 0.4f};
        unsigned int cc[3] = {(unsigned int)(packed & 0x1FFFFF),
                              (unsigned int)((packed >> 21) & 0x1FFFFF),
                              (unsigned int)(packed >> 42)};
        #pragma unroll
        for (int s2 = 0; s2 < 3; ++s2) {
            float sv  = scl[s2];
            float vol = __fmul_rn((float)(4.0 / 3.0 * M_PI),
                                  __fmul_rn(__fmul_rn(sv, sv), sv));
            density[i * 3 + s2] = (float)cc[s2] / vol;
            icnt[i * 3 + s2] = cc[s2];
        }
    }
}

// ---------------------------------------------------------------------------
// Kernel B: fused sums + embed + broadcast (byte-identical to R14). Wave 0
// reduces the 1024x3 integer counts -> exact S1,S2 in LDS. Block (c,g):
// embeds svec chunk c (16 rows x 64 hidden) into 4 KB LDS, then 32
// coalesced 4 KB stores to i-group g.
// ---------------------------------------------------------------------------
__global__ __launch_bounds__(256) void k_bcast(const float* __restrict__ density,
                                               const float* __restrict__ ent,
                                               const unsigned int* __restrict__ icnt,
                                               const float* __restrict__ Wm,
                                               const float* __restrict__ bm,
                                               const float* __restrict__ Wl,
                                               const float* __restrict__ bl,
                                               v4f* __restrict__ out) {
    __shared__ float  s_lds[16 * HID];
    __shared__ double sS[6];           // S1[0..2], S2[0..2]
    const int b    = blockIdx.x;
    const int c    = b & 63;           // 64 chunks of 16 rows
    const int g    = b >> 6;           // 32 i-groups of 32 rows
    const int t    = threadIdx.x;
    const int lane = t & 63;
    const int w    = t >> 6;

    // wave 0: exact integer sums over all rows (lane owns rows lane*16..+15)
    if (w == 0) {
        unsigned int sa0 = 0, sa1 = 0, sa2 = 0, sb0 = 0, sb1 = 0, sb2 = 0;
        #pragma unroll
        for (int r = 0; r < 16; ++r) {
            const int row = lane * 16 + r;
            unsigned int c0 = icnt[row * 3 + 0];
            unsigned int c1 = icnt[row * 3 + 1];
            unsigned int c2 = icnt[row * 3 + 2];
            sa0 += c0; sa1 += c1; sa2 += c2;
            sb0 += c0 * c0; sb1 += c1 * c1; sb2 += c2 * c2;
        }
        #pragma unroll
        for (int off = 32; off > 0; off >>= 1) {
            sa0 += __shfl_xor(sa0, off); sa1 += __shfl_xor(sa1, off);
            sa2 += __shfl_xor(sa2, off); sb0 += __shfl_xor(sb0, off);
            sb1 += __shfl_xor(sb1, off); sb2 += __shfl_xor(sb2, off);
        }
        if (lane == 0) {
            const float scl[3] = {0.1f, 0.2f, 0.4f};
            unsigned int A[3] = {sa0, sa1, sa2};
            unsigned int B[3] = {sb0, sb1, sb2};
            #pragma unroll
            for (int s = 0; s < 3; ++s) {
                float sv   = scl[s];
                float volf = __fmul_rn((float)(4.0 / 3.0 * M_PI),
                                       __fmul_rn(__fmul_rn(sv, sv), sv));
                double vold = (double)volf;
                sS[s]     = (double)A[s] / vold;
                sS[3 + s] = (double)B[s] / (vold * vold);
            }
        }
    }
    __syncthreads();

    double S1[3], S2[3];
    #pragma unroll
    for (int s = 0; s < 3; ++s) { S1[s] = sS[s]; S2[s] = sS[3 + s]; }

    #pragma unroll
    for (int kk = 0; kk < 4; ++kk) {
        const int row = 16 * c + 4 * w + kk;

        // mdve = l2norm([density(3), gradient(3)])
        float m6[6];
        double nrm6 = 0.0;
        #pragma unroll
        for (int s = 0; s < 3; ++s) {
            float d = density[row * 3 + s];
            m6[s] = d;
            double dd = (double)d;
            double g2 = 1024.0 * dd * dd - 2.0 * dd * S1[s] + S2[s];
            m6[3 + s] = (float)sqrt(g2 > 0.0 ? g2 : 1e-12);
        }
        #pragma unroll
        for (int s = 0; s < 6; ++s) nrm6 += (double)m6[s] * (double)m6[s];
        float inv6 = 1.0f / fmaxf((float)sqrt(nrm6), 1e-12f);
        #pragma unroll
        for (int s = 0; s < 6; ++s) m6[s] *= inv6;

        // lgee = l2norm(entropies(3))
        float l3[3];
        double nrm3 = 0.0;
        #pragma unroll
        for (int s = 0; s < 3; ++s) {
            l3[s] = ent[row * 3 + s];
            nrm3 += (double)l3[s] * (double)l3[s];
        }
        float inv3 = 1.0f / fmaxf((float)sqrt(nrm3), 1e-12f);
        #pragma unroll
        for (int s = 0; s < 3; ++s) l3[s] *= inv3;

        // y = l2norm(mdve @ Wm + bm) over the 64 hidden units (one wave)
        float y = bm[lane];
        #pragma unroll
        for (int s = 0; s < 6; ++s) y += m6[s] * Wm[s * HID + lane];
        float yy = y * y;
        #pragma unroll
        for (int off = 32; off > 0; off >>= 1) yy += __shfl_xor(yy, off);
        y *= 1.0f / fmaxf(sqrtf(yy), 1e-12f);

        // z = l2norm(lgee @ Wl + bl)
        float z = bl[lane];
        #pragma unroll
        for (int s = 0; s < 3; ++s) z += l3[s] * Wl[s * HID + lane];
        float zz = z * z;
        #pragma unroll
        for (int off = 32; off > 0; off >>= 1) zz += __shfl_xor(zz, off);
        z *= 1.0f / fmaxf(sqrtf(zz), 1e-12f);

        s_lds[(4 * w + kk) * HID + lane] = y + z;
    }
    __syncthreads();

    const v4f val = *(const v4f*)&s_lds[4 * t];   // registers

    v4f* dst = out + (size_t)(g * 32) * (NPTS * HID / 4) + c * 256 + t;
    #pragma unroll 4
    for (int ii = 0; ii < 32; ++ii) {
        *dst = val;
        dst += NPTS * HID / 4;                    // next i: +16384 v4f
    }
}

extern "C" void kernel_launch(void* const* d_in, const int* in_sizes, int n_in,
                              void* d_out, int out_size, void* d_ws, size_t ws_size,
                              hipStream_t stream) {
    const float* pts = (const float*)d_in[0];
    // d_in[1], d_in[2] (W_rtdie, b_rtdie) do not affect the output.
    const float* Wm = (const float*)d_in[3];
    const float* bm = (const float*)d_in[4];
    const float* Wl = (const float*)d_in[5];
    const float* bl = (const float*)d_in[6];

    char* ws = (char*)d_ws;
    float*        density = (float*)(ws);                 // 12288 B
    float*        entv    = (float*)(ws + 12288);         // 12288 B
    unsigned int* icnt    = (unsigned int*)(ws + 24576);  // 12288 B

    float* out = (float*)d_out;

    // MEASUREMENT PROBE: launch the (idempotent) k_rows twice; the marginal
    // dur_us vs R14's 68.5 is k_rows' standalone duration.
    hipLaunchKernelGGL(k_rows, dim3(NPTS), dim3(64), 0, stream,
                       pts, density, entv, icnt);
    hipLaunchKernelGGL(k_rows, dim3(NPTS), dim3(64), 0, stream,
                       pts, density, entv, icnt);
    hipLaunchKernelGGL(k_bcast, dim3(64 * 32), dim3(256), 0, stream,
                       density, entv, icnt, Wm, bm, Wl, bl, (v4f*)out);
}

// Round 18
// 68.059 us; speedup vs baseline: 1.2528x; 1.2528x over previous
//
#include <hip/hip_runtime.h>
#include <math.h>

#define NPTS 1024
#define HID 64

typedef float v4f __attribute__((ext_vector_type(4)));

// Keep-min-32 merge of two sorted-32 arrays (ascending): result = sorted
// smallest 32 of the union. Bitonic halver + 5-stage clean, all static.
#define MERGE32(S, O)                                            \
    do {                                                         \
        float _m[32];                                            \
        _Pragma("unroll")                                        \
        for (int _r = 0; _r < 32; ++_r)                          \
            _m[_r] = fminf((S)[_r], (O)[31 - _r]);               \
        _Pragma("unroll")                                        \
        for (int _j = 16; _j > 0; _j >>= 1) {                    \
            _Pragma("unroll")                                    \
            for (int _r = 0; _r < 32; ++_r) {                    \
                const int _l = _r ^ _j;                          \
                if (_l > _r) {                                   \
                    float _lo = fminf(_m[_r], _m[_l]);           \
                    float _hi = fmaxf(_m[_r], _m[_l]);           \
                    _m[_r] = _lo;                                \
                    _m[_l] = _hi;                                \
                }                                                \
            }                                                    \
        }                                                        \
        _Pragma("unroll")                                        \
        for (int _r = 0; _r < 32; ++_r) (S)[_r] = _m[_r];        \
    } while (0)

// ---------------------------------------------------------------------------
// Kernel A: one block (2 waves, 128 thr) per row i -> 2 waves/SIMD chip-wide
// (the 1-wave/SIMD version was latency-exposed at ~16 us). Wave w: 512
// distances (8/lane, exact fp32 on the count path), sort8, pad-to-32,
// 6-step butterfly keep-min-32 -> wave sorted-32 + packed counts. Barrier;
// wave 0 merges the two sorted-32s (exact, associative) and computes the
// identical R13 entropies -> outputs bit-identical to R13/R14.
// ---------------------------------------------------------------------------
__global__ __launch_bounds__(128) void k_rows(const float* __restrict__ pts,
                                              float* __restrict__ density,
                                              float* __restrict__ ent,
                                              unsigned int* __restrict__ icnt) {
    __shared__ float s_arr[32];
    __shared__ unsigned long long s_cnt;

    const int i    = blockIdx.x;
    const int t    = threadIdx.x;
    const int lane = t & 63;
    const int w    = t >> 6;

    const float px = pts[i * 3 + 0];
    const float py = pts[i * 3 + 1];
    const float pz = pts[i * 3 + 2];

    // 8 distances per lane (wave w covers j in [w*512, w*512+512)).
    float v[8];
    int c0 = 0, c1 = 0, c2 = 0;
    #pragma unroll
    for (int q = 0; q < 8; ++q) {
        const int j = w * 512 + q * 64 + lane;    // coalesced within wave
        // exact rounding, no fma contraction: ((dx*dx + dy*dy) + dz*dz)
        float dx = __fsub_rn(px, pts[j * 3 + 0]);
        float dy = __fsub_rn(py, pts[j * 3 + 1]);
        float dz = __fsub_rn(pz, pts[j * 3 + 2]);
        float d2 = __fadd_rn(__fadd_rn(__fmul_rn(dx, dx), __fmul_rn(dy, dy)),
                             __fmul_rn(dz, dz));
        float d = __fsqrt_rn(d2 > 0.0f ? d2 : 1e-12f);   // _safe_sqrt
        v[q] = d;
        c0 += (d < 0.1f);
        c1 += (d < 0.2f);
        c2 += (d < 0.4f);
    }

    // Pack per-wave counts (21-bit fields), butterfly reduce across the wave.
    unsigned long long packed = (unsigned long long)c0
                              | ((unsigned long long)c1 << 21)
                              | ((unsigned long long)c2 << 42);
    #pragma unroll
    for (int off = 32; off > 0; off >>= 1) packed += __shfl_xor(packed, off);
    if (w == 1 && lane == 0) s_cnt = packed;

    // ---- per-lane bitonic sort of the 8 values (ascending), pure VALU ----
    #pragma unroll
    for (int k = 2; k <= 8; k <<= 1) {
        #pragma unroll
        for (int j = k >> 1; j > 0; j >>= 1) {
            #pragma unroll
            for (int r = 0; r < 8; ++r) {
                const int l = r ^ j;
                if (l > r) {
                    const bool up = ((r & k) == 0);
                    float lo = fminf(v[r], v[l]);
                    float hi = fmaxf(v[r], v[l]);
                    v[r] = up ? lo : hi;
                    v[l] = up ? hi : lo;
                }
            }
        }
    }

    // ---- pad to sorted-32, butterfly keep-min-32 across the wave's lanes ----
    float s[32];
    #pragma unroll
    for (int r = 0; r < 32; ++r) s[r] = (r < 8) ? v[r] : 3.0e38f;

    #pragma unroll
    for (int step = 1; step < 64; step <<= 1) {
        float o[32];
        #pragma unroll
        for (int r = 0; r < 32; ++r) o[r] = __shfl_xor(s[r], step);
        MERGE32(s, o);
    }
    // s[0..31]: wave's sorted 32 smallest, identical in all lanes

    if (w == 1 && lane < 32) s_arr[lane] = s[lane];
    __syncthreads();

    if (w == 0) {
        float o[32];
        #pragma unroll
        for (int r = 0; r < 32; ++r) o[r] = s_arr[r];   // LDS broadcast
        MERGE32(s, o);
        // s[0..31]: global sorted 32 smallest (s[0] = self) — bit-identical
        // to the R13 single-wave result (keep-min-32 is associative).

        // entropies over ranks 1..k — IDENTICAL code/order to R13
        const int kvv[3] = {5, 10, 25};
        float E[3];
        #pragma unroll
        for (int q = 0; q < 3; ++q) {
            const int k = kvv[q];
            float S = 0.0f;
            #pragma unroll
            for (int r = 1; r <= 25; ++r) if (r <= k) S += s[r];
            float Ee = 0.0f;
            #pragma unroll
            for (int r = 1; r <= 25; ++r) if (r <= k) {
                float p = s[r] / S;
                Ee -= p * logf(p + 1e-10f);
            }
            E[q] = Ee;
        }

        if (lane == 0) {
            unsigned long long ptot = packed + s_cnt;
            ent[i * 3 + 0] = E[0];
            ent[i * 3 + 1] = E[1];
            ent[i * 3 + 2] = E[2];
            const float scl[3] = {0.1f, 0.2f, 0.4f};
            unsigned int cc[3] = {(unsigned int)(ptot & 0x1FFFFF),
                                  (unsigned int)((ptot >> 21) & 0x1FFFFF),
                                  (unsigned int)(ptot >> 42)};
            #pragma unroll
            for (int s2 = 0; s2 < 3; ++s2) {
                float sv  = scl[s2];
                float vol = __fmul_rn((float)(4.0 / 3.0 * M_PI),
                                      __fmul_rn(__fmul_rn(sv, sv), sv));
                density[i * 3 + s2] = (float)cc[s2] / vol;
                icnt[i * 3 + s2] = cc[s2];
            }
        }
    }
}

// ---------------------------------------------------------------------------
// Kernel B: fused sums + embed + broadcast (byte-identical to R14). Wave 0
// reduces the 1024x3 integer counts -> exact S1,S2 in LDS. Block (c,g):
// embeds svec chunk c (16 rows x 64 hidden) into 4 KB LDS, then 32
// coalesced 4 KB stores to i-group g.
// ---------------------------------------------------------------------------
__global__ __launch_bounds__(256) void k_bcast(const float* __restrict__ density,
                                               const float* __restrict__ ent,
                                               const unsigned int* __restrict__ icnt,
                                               const float* __restrict__ Wm,
                                               const float* __restrict__ bm,
                                               const float* __restrict__ Wl,
                                               const float* __restrict__ bl,
                                               v4f* __restrict__ out) {
    __shared__ float  s_lds[16 * HID];
    __shared__ double sS[6];           // S1[0..2], S2[0..2]
    const int b    = blockIdx.x;
    const int c    = b & 63;           // 64 chunks of 16 rows
    const int g    = b >> 6;           // 32 i-groups of 32 rows
    const int t    = threadIdx.x;
    const int lane = t & 63;
    const int w    = t >> 6;

    // wave 0: exact integer sums over all rows (lane owns rows lane*16..+15)
    if (w == 0) {
        unsigned int sa0 = 0, sa1 = 0, sa2 = 0, sb0 = 0, sb1 = 0, sb2 = 0;
        #pragma unroll
        for (int r = 0; r < 16; ++r) {
            const int row = lane * 16 + r;
            unsigned int c0 = icnt[row * 3 + 0];
            unsigned int c1 = icnt[row * 3 + 1];
            unsigned int c2 = icnt[row * 3 + 2];
            sa0 += c0; sa1 += c1; sa2 += c2;
            sb0 += c0 * c0; sb1 += c1 * c1; sb2 += c2 * c2;
        }
        #pragma unroll
        for (int off = 32; off > 0; off >>= 1) {
            sa0 += __shfl_xor(sa0, off); sa1 += __shfl_xor(sa1, off);
            sa2 += __shfl_xor(sa2, off); sb0 += __shfl_xor(sb0, off);
            sb1 += __shfl_xor(sb1, off); sb2 += __shfl_xor(sb2, off);
        }
        if (lane == 0) {
            const float scl[3] = {0.1f, 0.2f, 0.4f};
            unsigned int A[3] = {sa0, sa1, sa2};
            unsigned int B[3] = {sb0, sb1, sb2};
            #pragma unroll
            for (int s = 0; s < 3; ++s) {
                float sv   = scl[s];
                float volf = __fmul_rn((float)(4.0 / 3.0 * M_PI),
                                       __fmul_rn(__fmul_rn(sv, sv), sv));
                double vold = (double)volf;
                sS[s]     = (double)A[s] / vold;
                sS[3 + s] = (double)B[s] / (vold * vold);
            }
        }
    }
    __syncthreads();

    double S1[3], S2[3];
    #pragma unroll
    for (int s = 0; s < 3; ++s) { S1[s] = sS[s]; S2[s] = sS[3 + s]; }

    #pragma unroll
    for (int kk = 0; kk < 4; ++kk) {
        const int row = 16 * c + 4 * w + kk;

        // mdve = l2norm([density(3), gradient(3)])
        float m6[6];
        double nrm6 = 0.0;
        #pragma unroll
        for (int s = 0; s < 3; ++s) {
            float d = density[row * 3 + s];
            m6[s] = d;
            double dd = (double)d;
            double g2 = 1024.0 * dd * dd - 2.0 * dd * S1[s] + S2[s];
            m6[3 + s] = (float)sqrt(g2 > 0.0 ? g2 : 1e-12);
        }
        #pragma unroll
        for (int s = 0; s < 6; ++s) nrm6 += (double)m6[s] * (double)m6[s];
        float inv6 = 1.0f / fmaxf((float)sqrt(nrm6), 1e-12f);
        #pragma unroll
        for (int s = 0; s < 6; ++s) m6[s] *= inv6;

        // lgee = l2norm(entropies(3))
        float l3[3];
        double nrm3 = 0.0;
        #pragma unroll
        for (int s = 0; s < 3; ++s) {
            l3[s] = ent[row * 3 + s];
            nrm3 += (double)l3[s] * (double)l3[s];
        }
        float inv3 = 1.0f / fmaxf((float)sqrt(nrm3), 1e-12f);
        #pragma unroll
        for (int s = 0; s < 3; ++s) l3[s] *= inv3;

        // y = l2norm(mdve @ Wm + bm) over the 64 hidden units (one wave)
        float y = bm[lane];
        #pragma unroll
        for (int s = 0; s < 6; ++s) y += m6[s] * Wm[s * HID + lane];
        float yy = y * y;
        #pragma unroll
        for (int off = 32; off > 0; off >>= 1) yy += __shfl_xor(yy, off);
        y *= 1.0f / fmaxf(sqrtf(yy), 1e-12f);

        // z = l2norm(lgee @ Wl + bl)
        float z = bl[lane];
        #pragma unroll
        for (int s = 0; s < 3; ++s) z += l3[s] * Wl[s * HID + lane];
        float zz = z * z;
        #pragma unroll
        for (int off = 32; off > 0; off >>= 1) zz += __shfl_xor(zz, off);
        z *= 1.0f / fmaxf(sqrtf(zz), 1e-12f);

        s_lds[(4 * w + kk) * HID + lane] = y + z;
    }
    __syncthreads();

    const v4f val = *(const v4f*)&s_lds[4 * t];   // registers

    v4f* dst = out + (size_t)(g * 32) * (NPTS * HID / 4) + c * 256 + t;
    #pragma unroll 4
    for (int ii = 0; ii < 32; ++ii) {
        *dst = val;
        dst += NPTS * HID / 4;                    // next i: +16384 v4f
    }
}

extern "C" void kernel_launch(void* const* d_in, const int* in_sizes, int n_in,
                              void* d_out, int out_size, void* d_ws, size_t ws_size,
                              hipStream_t stream) {
    const float* pts = (const float*)d_in[0];
    // d_in[1], d_in[2] (W_rtdie, b_rtdie) do not affect the output.
    const float* Wm = (const float*)d_in[3];
    const float* bm = (const float*)d_in[4];
    const float* Wl = (const float*)d_in[5];
    const float* bl = (const float*)d_in[6];

    char* ws = (char*)d_ws;
    float*        density = (float*)(ws);                 // 12288 B
    float*        entv    = (float*)(ws + 12288);         // 12288 B
    unsigned int* icnt    = (unsigned int*)(ws + 24576);  // 12288 B

    float* out = (float*)d_out;

    hipLaunchKernelGGL(k_rows, dim3(NPTS), dim3(128), 0, stream,
                       pts, density, entv, icnt);
    hipLaunchKernelGGL(k_bcast, dim3(64 * 32), dim3(256), 0, stream,
                       density, entv, icnt, Wm, bm, Wl, bl, (v4f*)out);
}

// Round 19
// 62.886 us; speedup vs baseline: 1.3558x; 1.0823x over previous
//
#include <hip/hip_runtime.h>
#include <math.h>

#define NPTS 1024
#define HID 64

typedef float v4f __attribute__((ext_vector_type(4)));

// Keep-min-32 merge of two sorted-32 arrays (ascending): result = sorted
// smallest 32 of the union. Bitonic halver + 5-stage clean, all static.
#define MERGE32(S, O)                                            \
    do {                                                         \
        float _m[32];                                            \
        _Pragma("unroll")                                        \
        for (int _r = 0; _r < 32; ++_r)                          \
            _m[_r] = fminf((S)[_r], (O)[31 - _r]);               \
        _Pragma("unroll")                                        \
        for (int _j = 16; _j > 0; _j >>= 1) {                    \
            _Pragma("unroll")                                    \
            for (int _r = 0; _r < 32; ++_r) {                    \
                const int _l = _r ^ _j;                          \
                if (_l > _r) {                                   \
                    float _lo = fminf(_m[_r], _m[_l]);           \
                    float _hi = fmaxf(_m[_r], _m[_l]);           \
                    _m[_r] = _lo;                                \
                    _m[_l] = _hi;                                \
                }                                                \
            }                                                    \
        }                                                        \
        _Pragma("unroll")                                        \
        for (int _r = 0; _r < 32; ++_r) (S)[_r] = _m[_r];        \
    } while (0)

// ---------------------------------------------------------------------------
// Kernel A: ONE WAVE per row i (throughput-bound -> minimize ops, not waves).
// 16 distances/lane (exact fp32 on the density-count path); per-lane bitonic
// sort16; step-1 merge via explicit 16-shfl exchange (skips the inf-pad
// work); 5 full keep-min-32 butterfly steps. Entropy via
// E_k = log(S_k) - T_k/S_k (T = sum d log d): ONE __logf per lane + 6
// interleaved masked reduces (was 40 logf/lane, all-lane redundant).
// ---------------------------------------------------------------------------
__global__ __launch_bounds__(64) void k_rows(const float* __restrict__ pts,
                                             float* __restrict__ density,
                                             float* __restrict__ ent,
                                             unsigned int* __restrict__ icnt) {
    const int i    = blockIdx.x;
    const int lane = threadIdx.x;

    const float px = pts[i * 3 + 0];
    const float py = pts[i * 3 + 1];
    const float pz = pts[i * 3 + 2];

    // 16 distances per lane, registers only (static indices).
    float v[16];
    int c0 = 0, c1 = 0, c2 = 0;
    #pragma unroll
    for (int q = 0; q < 16; ++q) {
        const int j = lane + q * 64;              // coalesced across lanes
        // exact rounding, no fma contraction: ((dx*dx + dy*dy) + dz*dz)
        float dx = __fsub_rn(px, pts[j * 3 + 0]);
        float dy = __fsub_rn(py, pts[j * 3 + 1]);
        float dz = __fsub_rn(pz, pts[j * 3 + 2]);
        float d2 = __fadd_rn(__fadd_rn(__fmul_rn(dx, dx), __fmul_rn(dy, dy)),
                             __fmul_rn(dz, dz));
        float d = __fsqrt_rn(d2 > 0.0f ? d2 : 1e-12f);   // _safe_sqrt
        v[q] = d;
        c0 += (d < 0.1f);
        c1 += (d < 0.2f);
        c2 += (d < 0.4f);
    }

    // Pack counts into one ull (21-bit fields), single butterfly reduce.
    unsigned long long packed = (unsigned long long)c0
                              | ((unsigned long long)c1 << 21)
                              | ((unsigned long long)c2 << 42);
    #pragma unroll
    for (int off = 32; off > 0; off >>= 1) packed += __shfl_xor(packed, off);
    // every lane now holds the row totals

    // ---- per-lane bitonic sort of the 16 values (ascending), pure VALU ----
    #pragma unroll
    for (int k = 2; k <= 16; k <<= 1) {
        #pragma unroll
        for (int j = k >> 1; j > 0; j >>= 1) {
            #pragma unroll
            for (int r = 0; r < 16; ++r) {
                const int l = r ^ j;
                if (l > r) {
                    const bool up = ((r & k) == 0);
                    float lo = fminf(v[r], v[l]);
                    float hi = fmaxf(v[r], v[l]);
                    v[r] = up ? lo : hi;
                    v[l] = up ? hi : lo;
                }
            }
        }
    }

    // ---- step 1: explicit merge of two sorted-16s (skip inf-pad work) ----
    float s[32];
    {
        float o16[16];
        #pragma unroll
        for (int r = 0; r < 16; ++r) o16[r] = __shfl_xor(v[r], 1);
        #pragma unroll
        for (int r = 0; r < 16; ++r) { s[r] = v[r]; s[16 + r] = o16[15 - r]; }
        // [asc16, desc16] is bitonic -> 5-stage clean sorts ascending
        #pragma unroll
        for (int j = 16; j > 0; j >>= 1) {
            #pragma unroll
            for (int r = 0; r < 32; ++r) {
                const int l = r ^ j;
                if (l > r) {
                    float lo = fminf(s[r], s[l]);
                    float hi = fmaxf(s[r], s[l]);
                    s[r] = lo;
                    s[l] = hi;
                }
            }
        }
    }

    // ---- steps 2..32: butterfly keep-min-32 across the 64 lanes ----
    #pragma unroll
    for (int step = 2; step < 64; step <<= 1) {
        float o[32];
        #pragma unroll
        for (int r = 0; r < 32; ++r) o[r] = __shfl_xor(s[r], step);
        MERGE32(s, o);
    }
    // s[0..31]: global sorted 32 smallest (s[0] = self), identical in all lanes

    // ---- entropy tail: lane r owns rank r; 1 __logf/lane + 6 reduces ----
    float myv = 0.0f;
    #pragma unroll
    for (int r = 0; r < 32; ++r) myv = (lane == r) ? s[r] : myv;  // s uniform
    float mylog = myv * __logf(myv + 1e-10f);                     // d * log d

    const bool inA = (lane >= 1 && lane <= 5);
    const bool inB = (lane >= 6 && lane <= 10);
    const bool inC = (lane >= 11 && lane <= 25);
    float aD = inA ? myv : 0.0f, aT = inA ? mylog : 0.0f;
    float bD = inB ? myv : 0.0f, bT = inB ? mylog : 0.0f;
    float cD = inC ? myv : 0.0f, cT = inC ? mylog : 0.0f;
    #pragma unroll
    for (int off = 32; off > 0; off >>= 1) {
        aD += __shfl_xor(aD, off); aT += __shfl_xor(aT, off);
        bD += __shfl_xor(bD, off); bT += __shfl_xor(bT, off);
        cD += __shfl_xor(cD, off); cT += __shfl_xor(cT, off);
    }

    if (lane == 0) {
        float S5  = aD,      T5  = aT;
        float S10 = aD + bD, T10 = aT + bT;
        float S25 = S10 + cD, T25 = T10 + cT;
        // E_k = log(S_k) - T_k / S_k   (== -sum p log p, eps negligible)
        ent[i * 3 + 0] = __logf(S5)  - T5  / S5;
        ent[i * 3 + 1] = __logf(S10) - T10 / S10;
        ent[i * 3 + 2] = __logf(S25) - T25 / S25;

        const float scl[3] = {0.1f, 0.2f, 0.4f};
        unsigned int cc[3] = {(unsigned int)(packed & 0x1FFFFF),
                              (unsigned int)((packed >> 21) & 0x1FFFFF),
                              (unsigned int)(packed >> 42)};
        #pragma unroll
        for (int s2 = 0; s2 < 3; ++s2) {
            float sv  = scl[s2];
            float vol = __fmul_rn((float)(4.0 / 3.0 * M_PI),
                                  __fmul_rn(__fmul_rn(sv, sv), sv));
            density[i * 3 + s2] = (float)cc[s2] / vol;
            icnt[i * 3 + s2] = cc[s2];
        }
    }
}

// ---------------------------------------------------------------------------
// Kernel B: fused sums + embed + broadcast (byte-identical to R14). Wave 0
// reduces the 1024x3 integer counts -> exact S1,S2 in LDS. Block (c,g):
// embeds svec chunk c (16 rows x 64 hidden) into 4 KB LDS, then 32
// coalesced 4 KB stores to i-group g.
// ---------------------------------------------------------------------------
__global__ __launch_bounds__(256) void k_bcast(const float* __restrict__ density,
                                               const float* __restrict__ ent,
                                               const unsigned int* __restrict__ icnt,
                                               const float* __restrict__ Wm,
                                               const float* __restrict__ bm,
                                               const float* __restrict__ Wl,
                                               const float* __restrict__ bl,
                                               v4f* __restrict__ out) {
    __shared__ float  s_lds[16 * HID];
    __shared__ double sS[6];           // S1[0..2], S2[0..2]
    const int b    = blockIdx.x;
    const int c    = b & 63;           // 64 chunks of 16 rows
    const int g    = b >> 6;           // 32 i-groups of 32 rows
    const int t    = threadIdx.x;
    const int lane = t & 63;
    const int w    = t >> 6;

    // wave 0: exact integer sums over all rows (lane owns rows lane*16..+15)
    if (w == 0) {
        unsigned int sa0 = 0, sa1 = 0, sa2 = 0, sb0 = 0, sb1 = 0, sb2 = 0;
        #pragma unroll
        for (int r = 0; r < 16; ++r) {
            const int row = lane * 16 + r;
            unsigned int c0 = icnt[row * 3 + 0];
            unsigned int c1 = icnt[row * 3 + 1];
            unsigned int c2 = icnt[row * 3 + 2];
            sa0 += c0; sa1 += c1; sa2 += c2;
            sb0 += c0 * c0; sb1 += c1 * c1; sb2 += c2 * c2;
        }
        #pragma unroll
        for (int off = 32; off > 0; off >>= 1) {
            sa0 += __shfl_xor(sa0, off); sa1 += __shfl_xor(sa1, off);
            sa2 += __shfl_xor(sa2, off); sb0 += __shfl_xor(sb0, off);
            sb1 += __shfl_xor(sb1, off); sb2 += __shfl_xor(sb2, off);
        }
        if (lane == 0) {
            const float scl[3] = {0.1f, 0.2f, 0.4f};
            unsigned int A[3] = {sa0, sa1, sa2};
            unsigned int B[3] = {sb0, sb1, sb2};
            #pragma unroll
            for (int s = 0; s < 3; ++s) {
                float sv   = scl[s];
                float volf = __fmul_rn((float)(4.0 / 3.0 * M_PI),
                                       __fmul_rn(__fmul_rn(sv, sv), sv));
                double vold = (double)volf;
                sS[s]     = (double)A[s] / vold;
                sS[3 + s] = (double)B[s] / (vold * vold);
            }
        }
    }
    __syncthreads();

    double S1[3], S2[3];
    #pragma unroll
    for (int s = 0; s < 3; ++s) { S1[s] = sS[s]; S2[s] = sS[3 + s]; }

    #pragma unroll
    for (int kk = 0; kk < 4; ++kk) {
        const int row = 16 * c + 4 * w + kk;

        // mdve = l2norm([density(3), gradient(3)])
        float m6[6];
        double nrm6 = 0.0;
        #pragma unroll
        for (int s = 0; s < 3; ++s) {
            float d = density[row * 3 + s];
            m6[s] = d;
            double dd = (double)d;
            double g2 = 1024.0 * dd * dd - 2.0 * dd * S1[s] + S2[s];
            m6[3 + s] = (float)sqrt(g2 > 0.0 ? g2 : 1e-12);
        }
        #pragma unroll
        for (int s = 0; s < 6; ++s) nrm6 += (double)m6[s] * (double)m6[s];
        float inv6 = 1.0f / fmaxf((float)sqrt(nrm6), 1e-12f);
        #pragma unroll
        for (int s = 0; s < 6; ++s) m6[s] *= inv6;

        // lgee = l2norm(entropies(3))
        float l3[3];
        double nrm3 = 0.0;
        #pragma unroll
        for (int s = 0; s < 3; ++s) {
            l3[s] = ent[row * 3 + s];
            nrm3 += (double)l3[s] * (double)l3[s];
        }
        float inv3 = 1.0f / fmaxf((float)sqrt(nrm3), 1e-12f);
        #pragma unroll
        for (int s = 0; s < 3; ++s) l3[s] *= inv3;

        // y = l2norm(mdve @ Wm + bm) over the 64 hidden units (one wave)
        float y = bm[lane];
        #pragma unroll
        for (int s = 0; s < 6; ++s) y += m6[s] * Wm[s * HID + lane];
        float yy = y * y;
        #pragma unroll
        for (int off = 32; off > 0; off >>= 1) yy += __shfl_xor(yy, off);
        y *= 1.0f / fmaxf(sqrtf(yy), 1e-12f);

        // z = l2norm(lgee @ Wl + bl)
        float z = bl[lane];
        #pragma unroll
        for (int s = 0; s < 3; ++s) z += l3[s] * Wl[s * HID + lane];
        float zz = z * z;
        #pragma unroll
        for (int off = 32; off > 0; off >>= 1) zz += __shfl_xor(zz, off);
        z *= 1.0f / fmaxf(sqrtf(zz), 1e-12f);

        s_lds[(4 * w + kk) * HID + lane] = y + z;
    }
    __syncthreads();

    const v4f val = *(const v4f*)&s_lds[4 * t];   // registers

    v4f* dst = out + (size_t)(g * 32) * (NPTS * HID / 4) + c * 256 + t;
    #pragma unroll 4
    for (int ii = 0; ii < 32; ++ii) {
        *dst = val;
        dst += NPTS * HID / 4;                    // next i: +16384 v4f
    }
}

extern "C" void kernel_launch(void* const* d_in, const int* in_sizes, int n_in,
                              void* d_out, int out_size, void* d_ws, size_t ws_size,
                              hipStream_t stream) {
    const float* pts = (const float*)d_in[0];
    // d_in[1], d_in[2] (W_rtdie, b_rtdie) do not affect the output.
    const float* Wm = (const float*)d_in[3];
    const float* bm = (const float*)d_in[4];
    const float* Wl = (const float*)d_in[5];
    const float* bl = (const float*)d_in[6];

    char* ws = (char*)d_ws;
    float*        density = (float*)(ws);                 // 12288 B
    float*        entv    = (float*)(ws + 12288);         // 12288 B
    unsigned int* icnt    = (unsigned int*)(ws + 24576);  // 12288 B

    float* out = (float*)d_out;

    hipLaunchKernelGGL(k_rows, dim3(NPTS), dim3(64), 0, stream,
                       pts, density, entv, icnt);
    hipLaunchKernelGGL(k_bcast, dim3(64 * 32), dim3(256), 0, stream,
                       density, entv, icnt, Wm, bm, Wl, bl, (v4f*)out);
}